// Round 8
// baseline (1710.673 us; speedup 1.0000x reference)
//
#include <hip/hip_runtime.h>
#include <math.h>

// MetaNETS Langevin sampler, MI355X — round 8.
// R7 lesson: 1-wave/batch starves latency hiding (2 waves/SIMD). Back to R5's
// 4-wave shape; attack the half-width scalar phases instead:
//  - drift f1 folded into the zW1 phase, full 256-thread split-K over [z,r,t]
//  - all drift GEMV weights prep-transposed -> contiguous float4 streams
//  - f2 rides the dsumC phase; f3 || gz full-width split-K
//  - z/r/t live in one vin[] LDS vector (uniform f1 dot product)
// MFMA fwd/bwd (wave-local per m-tile, tau aliases h1f) unchanged from R6.

#define B_TOT 2048
#define NPT   64
#define ZD    64
#define HD    128

typedef short bh8 __attribute__((ext_vector_type(8)));   // 8 x bf16 (4 VGPR)
typedef float fx4 __attribute__((ext_vector_type(4)));   // MFMA C/D

__device__ __forceinline__ float sigf(float x) {
  return __builtin_amdgcn_rcpf(1.0f + __expf(-x));
}
__device__ __forceinline__ unsigned int bfb(float x) {   // fp32 -> bf16 bits (RNE)
  unsigned int u = __float_as_uint(x);
  u += 0x7FFFu + ((u >> 16) & 1u);
  return u >> 16;
}
__device__ __forceinline__ unsigned int packbf(float a, float b) {
  unsigned int ua = __float_as_uint(a), ub = __float_as_uint(b);
  ua += 0x7FFFu + ((ua >> 16) & 1u);
  ub += 0x7FFFu + ((ub >> 16) & 1u);
  return (ua >> 16) | (ub & 0xFFFF0000u);
}
__device__ __forceinline__ float wsum64(float v) {
  #pragma unroll
  for (int d = 1; d < 64; d <<= 1) v += __shfl_xor(v, d, 64);
  return v;
}
__device__ __forceinline__ void wave_sync() {   // intra-wave LDS order + drain
  __builtin_amdgcn_wave_barrier();
  __builtin_amdgcn_s_waitcnt(0xC07F);           // lgkmcnt(0)
  __builtin_amdgcn_wave_barrier();
}

// d_ws layout (floats): [0,32768) = 65536 bf16 frags (4 arrays of 16384)
//   arr0 Wd2, arr1 Wd2^T, arr2 We2, arr3 We3 (B-frag layout, see R5)
// [32768,40960)=Wd1zT[k*64+j]  [40960,66048)=Wf1T[h*196+j] (row:z64,r128,t,pad3)
// [66048,82432)=Wf2T[h*128+j]  [82432,90624)=Wf3T[z*128+h]
__global__ __launch_bounds__(256)
void prep_kernel(const float* __restrict__ Wd2, const float* __restrict__ We2,
                 const float* __restrict__ We3, const float* __restrict__ Wd1,
                 const float* __restrict__ Wf1, const float* __restrict__ Wf2,
                 const float* __restrict__ Wf3, ushort* __restrict__ ws) {
  const int id = blockIdx.x * 256 + threadIdx.x;
  float* fw = (float*)ws;
  if (id < 65536) {
    const int arr = id >> 14;
    const int e = id & 16383;
    const int j = e & 7, L = (e >> 3) & 63, nt = (e >> 9) & 7, kc = e >> 12;
    const int kk = kc * 32 + (L >> 4) * 8 + j, nn = nt * 16 + (L & 15);
    float v;
    if      (arr == 0) v = Wd2[kk * HD + nn];
    else if (arr == 1) v = Wd2[nn * HD + kk];    // Wd2^T
    else if (arr == 2) v = We2[kk * HD + nn];
    else               v = We3[kk * HD + nn];
    ws[id] = (ushort)bfb(v);
  } else if (id < 73728) {
    const int e = id - 65536;                    // Wd1zT[k*64+j]=Wd1[j*128+k]
    fw[32768 + e] = Wd1[(e & 63) * HD + (e >> 6)];
  } else if (id < 98816) {
    const int e = id - 73728;                    // Wf1T[h*196+j]
    const int h = e / 196, j = e - h * 196;
    fw[40960 + e] = (j < 193) ? Wf1[j * HD + h] : 0.0f;
  } else if (id < 115200) {
    const int e = id - 98816;                    // Wf2T[h*128+j]
    fw[66048 + e] = Wf2[(e & 127) * HD + (e >> 7)];
  } else if (id < 123392) {
    const int e = id - 115200;                   // Wf3T[z*128+h]
    fw[82432 + e] = Wf3[(e & 127) * ZD + (e >> 7)];
  }
}

__global__ __launch_bounds__(256, 1)
void metanets_kernel(
    const float* __restrict__ x_ctx, const float* __restrict__ y_ctx,
    const float* __restrict__ mask,  const float* __restrict__ z0,
    const float* __restrict__ noises,
    const float* __restrict__ We1, const float* __restrict__ be1,
    const float* __restrict__ be2, const float* __restrict__ be3,
    const float* __restrict__ Wd1, const float* __restrict__ bd1,
    const float* __restrict__ bd2, const float* __restrict__ Wd3,
    const float* __restrict__ bd3,
    const float* __restrict__ bf1, const float* __restrict__ bf2,
    const float* __restrict__ bf3,
    const ushort* __restrict__ wsfrag,
    float* __restrict__ out, int steps, float dt, float dco)
{
  __shared__ __align__(16) unsigned int h1f[4096];  // h1 / tau (aliased) A-frags
  __shared__ __align__(16) float vin[200];   // z[0:64) r[64:192) t[192] pad0
  __shared__ __align__(16) float zw1[128];
  __shared__ __align__(16) float scratchP[512];  // f1P | dsumP | f3P+gzP
  __shared__ __align__(16) float dsumC[128];
  __shared__ __align__(16) float f1sh[128];
  __shared__ __align__(16) float f2sh[128];
  __shared__ float bd2sh[128], wd3sh[128], wx0sh[128], wx1sh[128];

  unsigned int* const tauf = h1f;

  const int tid = threadIdx.x;
  const int lane = tid & 63;                                  // context point
  const int w = __builtin_amdgcn_readfirstlane(tid >> 6);     // wave = m-tile
  const int b = blockIdx.x;
  const int rr = lane & 15, qq = lane >> 4;

  const bh8* Wd2f  = (const bh8*)(wsfrag);
  const bh8* Wd2Tf = (const bh8*)(wsfrag + 16384);
  const bh8* We2f  = (const bh8*)(wsfrag + 32768);
  const bh8* We3f  = (const bh8*)(wsfrag + 49152);
  const float* fws   = (const float*)wsfrag;
  const float* Wd1zT = fws + 32768;
  const float* Wf1T  = fws + 40960;
  const float* Wf2T  = fws + 66048;
  const float* Wf3T  = fws + 82432;

  const float x0v = x_ctx[(b*NPT + lane)*2 + 0];
  const float x1v = x_ctx[(b*NPT + lane)*2 + 1];
  const float yv  = y_ctx[b*NPT + lane];
  const float mkv = mask[b*NPT + lane];
  const float inv_msum = 1.0f / fmaxf(wsum64(mkv), 1e-6f);
  const float bd3v = bd3[0];

  if (tid < 64) vin[tid] = z0[b*ZD + tid];
  if (tid >= 192) vin[tid - 192 + 192] = 0.0f;   // t=0 (step0) + pads, tid<200 range
  if (tid < 128) {
    bd2sh[tid] = bd2[tid];
    wd3sh[tid] = Wd3[tid];
    wx0sh[tid] = Wd1[64*HD + tid];
    wx1sh[tid] = Wd1[65*HD + tid];
  }
  __syncthreads();

  // ================= encoder =================
  #pragma unroll
  for (int quad = 0; quad < 4; ++quad) {       // enc L1 -> h1f (kc=w slice)
    unsigned int pw[4];
    #pragma unroll
    for (int jj = 0; jj < 8; jj += 2) {
      const int k = 32*w + 8*quad + jj;
      const float sA = be1[k]   + x0v*We1[k]   + x1v*We1[HD+k]   + yv*We1[2*HD+k];
      const float sB = be1[k+1] + x0v*We1[k+1] + x1v*We1[HD+k+1] + yv*We1[2*HD+k+1];
      pw[jj>>1] = packbf(sA*sigf(sA), sB*sigf(sB));
    }
    uint4 v4; v4.x = pw[0]; v4.y = pw[1]; v4.z = pw[2]; v4.w = pw[3];
    ((uint4*)h1f)[(w*4 + (lane>>4))*64 + quad*16 + (lane&15)] = v4;
  }
  __syncthreads();

  {  // enc L2 (MFMA) -> tauf (aliased)
    bh8 af[4];
    #pragma unroll
    for (int kc = 0; kc < 4; ++kc)
      af[kc] = ((const bh8*)h1f)[(kc*4 + w)*64 + lane];
    wave_sync();
    #pragma unroll 1
    for (int half = 0; half < 2; ++half) {
      const int h4 = half*4;
      fx4 acc[4];
      #pragma unroll
      for (int i = 0; i < 4; ++i) {
        const float bv = be2[(h4+i)*16 + rr];
        acc[i] = (fx4){bv, bv, bv, bv};
      }
      #pragma unroll
      for (int i = 0; i < 4; ++i) {
        const int nt = h4 + i;
        acc[i] = __builtin_amdgcn_mfma_f32_16x16x32_bf16(af[0], We2f[(0*8+nt)*64+lane], acc[i], 0,0,0);
        acc[i] = __builtin_amdgcn_mfma_f32_16x16x32_bf16(af[1], We2f[(1*8+nt)*64+lane], acc[i], 0,0,0);
        acc[i] = __builtin_amdgcn_mfma_f32_16x16x32_bf16(af[2], We2f[(2*8+nt)*64+lane], acc[i], 0,0,0);
        acc[i] = __builtin_amdgcn_mfma_f32_16x16x32_bf16(af[3], We2f[(3*8+nt)*64+lane], acc[i], 0,0,0);
      }
      #pragma unroll
      for (int i = 0; i < 4; ++i) {
        const int nt = h4 + i;
        #pragma unroll
        for (int g = 0; g < 4; ++g) {
          const float s2 = acc[i][g];
          const unsigned int tb = bfb(s2 * sigf(s2));
          const unsigned int pb = (unsigned int)__shfl_xor((int)tb, 1, 64);
          if ((rr & 1) == 0) {
            const int unit = ((nt>>1)*4 + w)*64 + (2*(nt&1) + (rr>>3))*16 + 4*qq + g;
            tauf[unit*4 + ((rr&7)>>1)] = tb | (pb << 16);
          }
        }
      }
    }
  }
  wave_sync();

  {  // enc L3 (MFMA) + masked mean-pool -> vin[64..192)
    float mkq[4];
    #pragma unroll
    for (int g = 0; g < 4; ++g) mkq[g] = __shfl(mkv, w*16 + qq*4 + g, 64);
    bh8 tf[4];
    #pragma unroll
    for (int kc = 0; kc < 4; ++kc)
      tf[kc] = ((const bh8*)tauf)[(kc*4 + w)*64 + lane];
    #pragma unroll 1
    for (int half = 0; half < 2; ++half) {
      const int h4 = half*4;
      fx4 acc[4];
      #pragma unroll
      for (int i = 0; i < 4; ++i) {
        const float bv = be3[(h4+i)*16 + rr];
        acc[i] = (fx4){bv, bv, bv, bv};
      }
      #pragma unroll
      for (int i = 0; i < 4; ++i) {
        const int nt = h4 + i;
        acc[i] = __builtin_amdgcn_mfma_f32_16x16x32_bf16(tf[0], We3f[(0*8+nt)*64+lane], acc[i], 0,0,0);
        acc[i] = __builtin_amdgcn_mfma_f32_16x16x32_bf16(tf[1], We3f[(1*8+nt)*64+lane], acc[i], 0,0,0);
        acc[i] = __builtin_amdgcn_mfma_f32_16x16x32_bf16(tf[2], We3f[(2*8+nt)*64+lane], acc[i], 0,0,0);
        acc[i] = __builtin_amdgcn_mfma_f32_16x16x32_bf16(tf[3], We3f[(3*8+nt)*64+lane], acc[i], 0,0,0);
      }
      #pragma unroll
      for (int i = 0; i < 4; ++i) {
        float pv = mkq[0]*acc[i][0] + mkq[1]*acc[i][1]
                 + mkq[2]*acc[i][2] + mkq[3]*acc[i][3];
        pv += __shfl_xor(pv, 16, 64);
        pv += __shfl_xor(pv, 32, 64);
        if (lane < 16) scratchP[w*128 + (h4+i)*16 + lane] = pv;
      }
    }
  }
  __syncthreads();
  if (tid < 128)
    vin[64 + tid] = (scratchP[tid] + scratchP[128+tid]
                   + scratchP[256+tid] + scratchP[384+tid]) * inv_msum;
  __syncthreads();

  // ================= Langevin step loop =================
  for (int st = 0; st < steps; ++st) {
    const float t = (float)st * dt;

    // P1: f1 partials (all 256, split-K over vin[0..196)) + zW1 (tid<128)
    {
      const int h = tid & 127, half = tid >> 7;
      float p0 = half ? 0.0f : bf1[h];
      float p1 = 0.f, p2 = 0.f, p3 = 0.f;
      const float4* wrow = (const float4*)(Wf1T + h*196) + half*24;
      const float4* vv4  = (const float4*)vin + half*24;
      const int n4 = half ? 25 : 24;
      #pragma unroll 4
      for (int q4 = 0; q4 < n4; ++q4) {
        const float4 wv = wrow[q4]; const float4 vv = vv4[q4];
        p0 = fmaf(vv.x, wv.x, p0); p1 = fmaf(vv.y, wv.y, p1);
        p2 = fmaf(vv.z, wv.z, p2); p3 = fmaf(vv.w, wv.w, p3);
      }
      scratchP[tid] = (p0+p1) + (p2+p3);
    }
    if (tid < 128) {
      float a0 = bd1[tid], a1 = 0.f, a2 = 0.f, a3 = 0.f;
      const float4* wz = (const float4*)(Wd1zT + tid*64);
      #pragma unroll 4
      for (int q4 = 0; q4 < 16; ++q4) {
        const float4 wv = wz[q4]; const float4 zv = ((const float4*)vin)[q4];
        a0 = fmaf(zv.x, wv.x, a0); a1 = fmaf(zv.y, wv.y, a1);
        a2 = fmaf(zv.z, wv.z, a2); a3 = fmaf(zv.w, wv.w, a3);
      }
      zw1[tid] = (a0+a1) + (a2+a3);
    }
    __syncthreads();   // s1

    // P2: dec L1 -> h1f (kc=w slice) + f1 combine
    #pragma unroll
    for (int quad = 0; quad < 4; ++quad) {
      unsigned int pw[4];
      #pragma unroll
      for (int jj = 0; jj < 8; jj += 2) {
        const int k = 32*w + 8*quad + jj;
        const float sA = zw1[k]   + x0v*wx0sh[k]   + x1v*wx1sh[k];
        const float sB = zw1[k+1] + x0v*wx0sh[k+1] + x1v*wx1sh[k+1];
        pw[jj>>1] = packbf(sA*sigf(sA), sB*sigf(sB));
      }
      uint4 v4; v4.x = pw[0]; v4.y = pw[1]; v4.z = pw[2]; v4.w = pw[3];
      ((uint4*)h1f)[(w*4 + (lane>>4))*64 + quad*16 + (lane&15)] = v4;
    }
    if (tid < 128) {
      const float a = scratchP[tid] + scratchP[tid + 128];
      f1sh[tid] = a * sigf(a);
    }
    __syncthreads();   // s2

    // P3+P4: fused fwd+bwd per wave's m-tile (wave-local; tau aliases h1f)
    {
      bh8 af[4];
      #pragma unroll
      for (int kc = 0; kc < 4; ++kc)
        af[kc] = ((const bh8*)h1f)[(kc*4 + w)*64 + lane];
      wave_sync();
      float x0q[4], x1q[4], yq[4], mkq[4];
      #pragma unroll
      for (int g = 0; g < 4; ++g) {
        const int src = w*16 + qq*4 + g;
        x0q[g] = __shfl(x0v, src, 64);
        x1q[g] = __shfl(x1v, src, 64);
        yq[g]  = __shfl(yv,  src, 64);
        mkq[g] = __shfl(mkv, src, 64);
      }
      float da[4] = {0.f, 0.f, 0.f, 0.f};
      #pragma unroll 1
      for (int half = 0; half < 2; ++half) {
        const int h4 = half*4;
        fx4 acc[4];
        #pragma unroll
        for (int i = 0; i < 4; ++i) {
          const float bv = bd2sh[(h4+i)*16 + rr];
          acc[i] = (fx4){bv, bv, bv, bv};
        }
        #pragma unroll
        for (int i = 0; i < 4; ++i) {
          const int nt = h4 + i;
          acc[i] = __builtin_amdgcn_mfma_f32_16x16x32_bf16(af[0], Wd2f[(0*8+nt)*64+lane], acc[i], 0,0,0);
          acc[i] = __builtin_amdgcn_mfma_f32_16x16x32_bf16(af[1], Wd2f[(1*8+nt)*64+lane], acc[i], 0,0,0);
          acc[i] = __builtin_amdgcn_mfma_f32_16x16x32_bf16(af[2], Wd2f[(2*8+nt)*64+lane], acc[i], 0,0,0);
          acc[i] = __builtin_amdgcn_mfma_f32_16x16x32_bf16(af[3], Wd2f[(3*8+nt)*64+lane], acc[i], 0,0,0);
        }
        #pragma unroll
        for (int i = 0; i < 4; ++i) {
          const int nt = h4 + i;
          const float w3 = wd3sh[nt*16 + rr];
          #pragma unroll
          for (int g = 0; g < 4; ++g) {
            const float s2 = acc[i][g];
            const float sg = sigf(s2);
            da[g] = fmaf(s2*sg, w3, da[g]);
            const unsigned int tb = bfb(w3 * (sg * fmaf(s2, 1.0f - sg, 1.0f)));
            const unsigned int pb = (unsigned int)__shfl_xor((int)tb, 1, 64);
            if ((rr & 1) == 0) {
              const int unit = ((nt>>1)*4 + w)*64 + (2*(nt&1) + (rr>>3))*16 + 4*qq + g;
              tauf[unit*4 + ((rr&7)>>1)] = tb | (pb << 16);
            }
          }
        }
      }
      float ebw[4];
      #pragma unroll
      for (int g = 0; g < 4; ++g) {
        float v = da[g];
        v += __shfl_xor(v, 1, 64);
        v += __shfl_xor(v, 2, 64);
        v += __shfl_xor(v, 4, 64);
        v += __shfl_xor(v, 8, 64);
        ebw[g] = t * mkq[g] * (v + bd3v - yq[g]);
      }
      wave_sync();   // tau scatter visible (wave-local)
      bh8 tf[4];
      #pragma unroll
      for (int kc = 0; kc < 4; ++kc)
        tf[kc] = ((const bh8*)tauf)[(kc*4 + w)*64 + lane];
      #pragma unroll 1
      for (int half = 0; half < 2; ++half) {
        const int h4 = half*4;
        fx4 u[4];
        #pragma unroll
        for (int i = 0; i < 4; ++i) u[i] = (fx4){0.f, 0.f, 0.f, 0.f};
        #pragma unroll
        for (int i = 0; i < 4; ++i) {
          const int nt = h4 + i;
          u[i] = __builtin_amdgcn_mfma_f32_16x16x32_bf16(tf[0], Wd2Tf[(0*8+nt)*64+lane], u[i], 0,0,0);
          u[i] = __builtin_amdgcn_mfma_f32_16x16x32_bf16(tf[1], Wd2Tf[(1*8+nt)*64+lane], u[i], 0,0,0);
          u[i] = __builtin_amdgcn_mfma_f32_16x16x32_bf16(tf[2], Wd2Tf[(2*8+nt)*64+lane], u[i], 0,0,0);
          u[i] = __builtin_amdgcn_mfma_f32_16x16x32_bf16(tf[3], Wd2Tf[(3*8+nt)*64+lane], u[i], 0,0,0);
        }
        #pragma unroll
        for (int i = 0; i < 4; ++i) {
          const int nt = h4 + i;
          const int k = nt*16 + rr;
          const float zv = zw1[k];
          const float wa = wx0sh[k];
          const float wb = wx1sh[k];
          float snt = 0.f;
          #pragma unroll
          for (int g = 0; g < 4; ++g) {
            const float s1 = zv + x0q[g]*wa + x1q[g]*wb;
            const float sg = sigf(s1);
            snt += ebw[g] * (sg * fmaf(s1, 1.0f - sg, 1.0f)) * u[i][g];
          }
          snt += __shfl_xor(snt, 16, 64);
          snt += __shfl_xor(snt, 32, 64);
          if (lane < 16) scratchP[w*128 + nt*16 + lane] = snt;   // dsumP
        }
      }
    }
    __syncthreads();   // s3

    // P5: dsum combine + drift f2 (tid<128, float4 streams)
    if (tid < 128) {
      dsumC[tid] = scratchP[tid] + scratchP[128+tid]
                 + scratchP[256+tid] + scratchP[384+tid];
      float p0 = bf2[tid], p1 = 0.f, p2 = 0.f, p3 = 0.f;
      const float4* wrow = (const float4*)(Wf2T + tid*128);
      #pragma unroll 4
      for (int q4 = 0; q4 < 32; ++q4) {
        const float4 wv = wrow[q4]; const float4 fv = ((const float4*)f1sh)[q4];
        p0 = fmaf(fv.x, wv.x, p0); p1 = fmaf(fv.y, wv.y, p1);
        p2 = fmaf(fv.z, wv.z, p2); p3 = fmaf(fv.w, wv.w, p3);
      }
      const float a = (p0+p1) + (p2+p3);
      f2sh[tid] = a * sigf(a);
    }
    __syncthreads();   // s4

    // P6: f3 partials (tid<128) || gz partials (tid>=128), split-K halves
    if (tid < 128) {
      const int j = tid & 63, hh = tid >> 6;
      float p0 = hh ? 0.0f : bf3[j];
      float p1 = 0.f, p2 = 0.f, p3 = 0.f;
      const float4* wrow = (const float4*)(Wf3T + j*128) + hh*16;
      const float4* fv4  = (const float4*)f2sh + hh*16;
      #pragma unroll 4
      for (int q4 = 0; q4 < 16; ++q4) {
        const float4 wv = wrow[q4]; const float4 fv = fv4[q4];
        p0 = fmaf(fv.x, wv.x, p0); p1 = fmaf(fv.y, wv.y, p1);
        p2 = fmaf(fv.z, wv.z, p2); p3 = fmaf(fv.w, wv.w, p3);
      }
      scratchP[tid] = (p0+p1) + (p2+p3);       // f3P
    } else {
      const int e = tid - 128;
      const int j = e & 63, hh = e >> 6;
      float p0 = 0.f, p1 = 0.f, p2 = 0.f, p3 = 0.f;
      const float4* wrow = (const float4*)(Wd1 + j*HD) + hh*16;   // Wd1 row j
      const float4* dv4  = (const float4*)dsumC + hh*16;
      #pragma unroll 4
      for (int q4 = 0; q4 < 16; ++q4) {
        const float4 wv = wrow[q4]; const float4 dv = dv4[q4];
        p0 = fmaf(dv.x, wv.x, p0); p1 = fmaf(dv.y, wv.y, p1);
        p2 = fmaf(dv.z, wv.z, p2); p3 = fmaf(dv.w, wv.w, p3);
      }
      scratchP[tid] = (p0+p1) + (p2+p3);       // gzP
    }
    __syncthreads();   // s5

    // P7: z update (+ next-step t into vin[192])
    if (tid < 64) {
      const float bj  = scratchP[tid] + scratchP[tid + 64];
      const float gzv = scratchP[tid + 128] + scratchP[tid + 192];
      const float zold = vin[tid];
      float g = zold + gzv;                    // t folded into ebw
      g = fminf(fmaxf(g, -100.0f), 100.0f);
      vin[tid] = zold + (bj - g) * dt
               + dco * noises[(size_t)st * (B_TOT * ZD) + b * ZD + tid];
    }
    if (tid == 64) vin[192] = (float)(st + 1) * dt;
    __syncthreads();   // s6
  }

  if (tid < 64) out[b * ZD + tid] = vin[tid];
}

extern "C" void kernel_launch(void* const* d_in, const int* in_sizes, int n_in,
                              void* d_out, int out_size, void* d_ws, size_t ws_size,
                              hipStream_t stream) {
  const float* x_ctx  = (const float*)d_in[0];
  const float* y_ctx  = (const float*)d_in[1];
  const float* mask   = (const float*)d_in[2];
  const float* z0     = (const float*)d_in[3];
  const float* noises = (const float*)d_in[4];
  const float* We1 = (const float*)d_in[5];  const float* be1 = (const float*)d_in[6];
  const float* We2 = (const float*)d_in[7];  const float* be2 = (const float*)d_in[8];
  const float* We3 = (const float*)d_in[9];  const float* be3 = (const float*)d_in[10];
  const float* Wd1 = (const float*)d_in[11]; const float* bd1 = (const float*)d_in[12];
  const float* Wd2 = (const float*)d_in[13]; const float* bd2 = (const float*)d_in[14];
  const float* Wd3 = (const float*)d_in[15]; const float* bd3 = (const float*)d_in[16];
  const float* Wf1 = (const float*)d_in[17]; const float* bf1 = (const float*)d_in[18];
  const float* Wf2 = (const float*)d_in[19]; const float* bf2 = (const float*)d_in[20];
  const float* Wf3 = (const float*)d_in[21]; const float* bf3 = (const float*)d_in[22];

  const int steps = in_sizes[4] / (B_TOT * ZD);
  const float dt  = 1.0f / (float)steps;
  const float dco = (float)sqrt(2.0 / (double)steps);

  ushort* wsu = (ushort*)d_ws;   // 128KB frags + ~232KB fp32 transposed arrays

  hipLaunchKernelGGL(prep_kernel, dim3(482), dim3(256), 0, stream,
                     Wd2, We2, We3, Wd1, Wf1, Wf2, Wf3, wsu);
  hipLaunchKernelGGL(metanets_kernel, dim3(B_TOT), dim3(256), 0, stream,
      x_ctx, y_ctx, mask, z0, noises,
      We1, be1, be2, be3,
      Wd1, bd1, bd2, Wd3, bd3,
      bf1, bf2, bf3,
      wsu, (float*)d_out, steps, dt, dco);
}